// Round 1
// baseline (3373.512 us; speedup 1.0000x reference)
//
#include <hip/hip_runtime.h>
#include <cstdint>
#include <cstddef>

// ---------- types / helpers ----------
typedef __attribute__((ext_vector_type(8))) short short8;   // 8 x bf16 (4 VGPRs)
typedef __attribute__((ext_vector_type(4))) float floatx4;  // 4 x f32 accum

__device__ __forceinline__ float bf2f(unsigned short u) {
    union { float f; uint32_t i; } v; v.i = ((uint32_t)u) << 16; return v.f;
}
__device__ __forceinline__ unsigned short f2bf(float f) {
    union { float f; uint32_t i; } v; v.f = f;
    uint32_t r = v.i + 0x7FFFu + ((v.i >> 16) & 1u);  // round-nearest-even
    return (unsigned short)(r >> 16);
}

// ---------- fused add + RMSNorm -> bf16 ----------
__global__ __launch_bounds__(256)
void add_rmsnorm_kernel(const float* __restrict__ x, const float* __restrict__ res,
                        const float* __restrict__ w, unsigned short* __restrict__ out,
                        int H, float invH)
{
    const size_t row = blockIdx.x;
    const float4* xv = (const float4*)(x + row * (size_t)H);
    const float4* rv = (const float4*)(res + row * (size_t)H);
    const float4* wv = (const float4*)w;
    const int nvec = H >> 2;
    float4 h[8];
    float s = 0.f;
    int cnt = 0;
    for (int idx = threadIdx.x; idx < nvec; idx += 256) {
        float4 a = xv[idx], b = rv[idx];
        float4 hh = make_float4(a.x + b.x, a.y + b.y, a.z + b.z, a.w + b.w);
        h[cnt++] = hh;
        s += hh.x * hh.x + hh.y * hh.y + hh.z * hh.z + hh.w * hh.w;
    }
    __shared__ float red[256];
    red[threadIdx.x] = s;
    __syncthreads();
    for (int off = 128; off > 0; off >>= 1) {
        if (threadIdx.x < off) red[threadIdx.x] += red[threadIdx.x + off];
        __syncthreads();
    }
    const float scale = rsqrtf(red[0] * invH + 1e-5f);
    ushort4* ov = (ushort4*)(out + row * (size_t)H);
    cnt = 0;
    for (int idx = threadIdx.x; idx < nvec; idx += 256) {
        float4 hh = h[cnt++];
        float4 ww = wv[idx];
        ushort4 o;
        o.x = f2bf(hh.x * scale * ww.x);
        o.y = f2bf(hh.y * scale * ww.y);
        o.z = f2bf(hh.z * scale * ww.z);
        o.w = f2bf(hh.w * scale * ww.w);
        ov[idx] = o;
    }
}

// ---------- fp32 [P,Q] -> bf16 [Q,P] transpose+cast ----------
__global__ __launch_bounds__(256)
void transpose_cast(const float* __restrict__ src, unsigned short* __restrict__ dst,
                    int P, int Q)
{
    __shared__ float tile[32][33];
    const int qt = blockIdx.x * 32, pt = blockIdx.y * 32;
    const int tx = threadIdx.x, ty = threadIdx.y;  // (32,8)
    #pragma unroll
    for (int r = 0; r < 32; r += 8) {
        int p = pt + ty + r, q = qt + tx;
        tile[ty + r][tx] = (p < P && q < Q) ? src[(size_t)p * Q + q] : 0.f;
    }
    __syncthreads();
    #pragma unroll
    for (int r = 0; r < 32; r += 8) {
        int q = qt + ty + r, p = pt + tx;
        if (q < Q && p < P) dst[(size_t)q * P + p] = f2bf(tile[tx][ty + r]);
    }
}

// ---------- GEMM: C[M,N] = A[M,K] x Bt[N,K]^T (bf16 in, fp32 acc) ----------
// EPI 0: store bf16   EPI 1: store fp32   EPI 2: store bf16( silu(acc) * other )
// Requires M % 128 == 0. N, K arbitrary (K tail zero-padded, K % 8 == 0 assumed).
template<int EPI>
__global__ __launch_bounds__(256)
void gemm128(const unsigned short* __restrict__ A,
             const unsigned short* __restrict__ Bt,
             void* __restrict__ Cv,
             const unsigned short* __restrict__ other,
             int M, int N, int K)
{
    __shared__ unsigned short As[128 * 40];  // 128 rows x 32 k, pad to 40
    __shared__ unsigned short Bs[128 * 40];
    const int tid  = threadIdx.x;
    const int m0   = blockIdx.y << 7;
    const int n0   = blockIdx.x << 7;
    const int lane = tid & 63;
    const int wave = tid >> 6;
    const int quad = lane >> 4;
    const int lr   = lane & 15;
    const int wm   = (wave >> 1) << 6;  // wave row offset within 128-tile
    const int wn   = (wave & 1) << 6;   // wave col offset

    const floatx4 zero = {0.f, 0.f, 0.f, 0.f};
    floatx4 acc[4][4];
    #pragma unroll
    for (int i = 0; i < 4; i++)
        #pragma unroll
        for (int j = 0; j < 4; j++) acc[i][j] = zero;

    // staging: each thread loads two 16B chunks per tile per matrix
    const int r0  = tid >> 2;        // 0..63
    const int kc0 = (tid & 3) << 3;  // 0,8,16,24

    for (int k0 = 0; k0 < K; k0 += 32) {
        const bool kok = (k0 + kc0 + 8) <= K;
        uint4 av0 = {0,0,0,0}, av1 = {0,0,0,0}, bv0 = {0,0,0,0}, bv1 = {0,0,0,0};
        if (kok) {
            av0 = *(const uint4*)(A + (size_t)(m0 + r0) * K + k0 + kc0);
            av1 = *(const uint4*)(A + (size_t)(m0 + r0 + 64) * K + k0 + kc0);
            if (n0 + r0 < N)
                bv0 = *(const uint4*)(Bt + (size_t)(n0 + r0) * K + k0 + kc0);
            if (n0 + r0 + 64 < N)
                bv1 = *(const uint4*)(Bt + (size_t)(n0 + r0 + 64) * K + k0 + kc0);
        }
        *(uint4*)(As + (r0)      * 40 + kc0) = av0;
        *(uint4*)(As + (r0 + 64) * 40 + kc0) = av1;
        *(uint4*)(Bs + (r0)      * 40 + kc0) = bv0;
        *(uint4*)(Bs + (r0 + 64) * 40 + kc0) = bv1;
        __syncthreads();

        short8 af[4], bfr[4];
        #pragma unroll
        for (int mi = 0; mi < 4; mi++)
            af[mi] = *(const short8*)(As + (wm + mi * 16 + lr) * 40 + quad * 8);
        #pragma unroll
        for (int ni = 0; ni < 4; ni++)
            bfr[ni] = *(const short8*)(Bs + (wn + ni * 16 + lr) * 40 + quad * 8);
        #pragma unroll
        for (int mi = 0; mi < 4; mi++)
            #pragma unroll
            for (int ni = 0; ni < 4; ni++)
                acc[mi][ni] = __builtin_amdgcn_mfma_f32_16x16x32_bf16(
                    af[mi], bfr[ni], acc[mi][ni], 0, 0, 0);
        __syncthreads();
    }

    // epilogue: D row = quad*4 + i, col = lr  (within each 16x16 tile)
    #pragma unroll
    for (int mi = 0; mi < 4; mi++) {
        const int growb = m0 + wm + mi * 16 + quad * 4;
        #pragma unroll
        for (int ni = 0; ni < 4; ni++) {
            const int col = n0 + wn + ni * 16 + lr;
            if (col < N) {
                #pragma unroll
                for (int i = 0; i < 4; i++) {
                    const size_t idx = (size_t)(growb + i) * N + col;
                    const float v = acc[mi][ni][i];
                    if (EPI == 0) {
                        ((unsigned short*)Cv)[idx] = f2bf(v);
                    } else if (EPI == 1) {
                        ((float*)Cv)[idx] = v;
                    } else {
                        const float o = bf2f(other[idx]);
                        const float sg = v / (1.f + __expf(-v));  // silu
                        ((unsigned short*)Cv)[idx] = f2bf(sg * o);
                    }
                }
            }
        }
    }
}

// ---------- launch ----------
extern "C" void kernel_launch(void* const* d_in, const int* in_sizes, int n_in,
                              void* d_out, int out_size, void* d_ws, size_t ws_size,
                              hipStream_t stream)
{
    const float* x   = (const float*)d_in[0];
    const float* res = (const float*)d_in[1];
    const float* lnw = (const float*)d_in[2];
    const float* wgv = (const float*)d_in[3];  // [H,R]
    const float* wgu = (const float*)d_in[4];  // [R,I]
    const float* wuv = (const float*)d_in[5];  // [H,R]
    const float* wuu = (const float*)d_in[6];  // [R,I]
    const float* wdv = (const float*)d_in[7];  // [I,R]
    const float* wdu = (const float*)d_in[8];  // [R,H]

    const int H = in_sizes[2];
    const int T = (int)((long long)in_sizes[0] / H);  // B*S = 8192
    const int R = in_sizes[3] / H;                    // 1592
    const int I = in_sizes[4] / R;                    // 14336

    // workspace layout (bf16 elements)
    unsigned short* p = (unsigned short*)d_ws;
    unsigned short* Wgv_t = p; p += (size_t)R * H;  // [R,H]
    unsigned short* Wuv_t = p; p += (size_t)R * H;  // [R,H]
    unsigned short* Wgu_t = p; p += (size_t)I * R;  // [I,R]
    unsigned short* Wuu_t = p; p += (size_t)I * R;  // [I,R]
    unsigned short* Wdv_t = p; p += (size_t)R * I;  // [R,I]
    unsigned short* Wdu_t = p; p += (size_t)H * R;  // [H,R]
    unsigned short* nbuf  = p; p += (size_t)T * H;  // [T,H]
    unsigned short* g1    = p; p += (size_t)T * R;  // [T,R]
    unsigned short* u1    = p; p += (size_t)T * R;  // [T,R]
    unsigned short* upm   = p; p += (size_t)T * I;  // [T,I] up, then m in-place
    unsigned short* d1    = nbuf;                   // [T,R] aliases nbuf (free after GEMM2)

    dim3 tb(32, 8);
    transpose_cast<<<dim3((R + 31) / 32, (H + 31) / 32), tb, 0, stream>>>(wgv, Wgv_t, H, R);
    transpose_cast<<<dim3((R + 31) / 32, (H + 31) / 32), tb, 0, stream>>>(wuv, Wuv_t, H, R);
    transpose_cast<<<dim3((I + 31) / 32, (R + 31) / 32), tb, 0, stream>>>(wgu, Wgu_t, R, I);
    transpose_cast<<<dim3((I + 31) / 32, (R + 31) / 32), tb, 0, stream>>>(wuu, Wuu_t, R, I);
    transpose_cast<<<dim3((R + 31) / 32, (I + 31) / 32), tb, 0, stream>>>(wdv, Wdv_t, I, R);
    transpose_cast<<<dim3((H + 31) / 32, (R + 31) / 32), tb, 0, stream>>>(wdu, Wdu_t, R, H);

    add_rmsnorm_kernel<<<T, 256, 0, stream>>>(x, res, lnw, nbuf, H, 1.0f / (float)H);

    dim3 gR((R + 127) / 128, T / 128);
    dim3 gI((I + 127) / 128, T / 128);
    dim3 gH((H + 127) / 128, T / 128);

    // g1 = n @ Wgv ; u1 = n @ Wuv
    gemm128<0><<<gR, 256, 0, stream>>>(nbuf, Wgv_t, g1, nullptr, T, R, H);
    gemm128<0><<<gR, 256, 0, stream>>>(nbuf, Wuv_t, u1, nullptr, T, R, H);
    // up = u1 @ Wuu
    gemm128<0><<<gI, 256, 0, stream>>>(u1, Wuu_t, upm, nullptr, T, I, R);
    // m = silu(g1 @ Wgu) * up   (in place over upm)
    gemm128<2><<<gI, 256, 0, stream>>>(g1, Wgu_t, upm, upm, T, I, R);
    // d1 = m @ Wdv
    gemm128<0><<<gR, 256, 0, stream>>>(upm, Wdv_t, d1, nullptr, T, R, I);
    // out = d1 @ Wdu  (fp32)
    gemm128<1><<<gH, 256, 0, stream>>>(d1, Wdu_t, d_out, nullptr, T, H, R);
}